// Round 4
// baseline (612.790 us; speedup 1.0000x reference)
//
#include <hip/hip_runtime.h>

// out[b, bin, d] = ce[chr[b]-1, d]; tensor (512,2001) unused, chr (512,) i32,
// ce (24,128) f32, out (512,2001,128) f32 = 524.5 MB. Pure write-BW-bound.
// v4 DIAGNOSTIC: identical store kernel launched twice — once into d_out
// (correctness) and once into d_ws (guarded by ws_size; ws appears to be
// ~3x out). The dur_us delta vs R3's 512 us measures the kernel's marginal
// store bandwidth: +83 us => 6.3 TB/s (at floor), +175 us => ~3 TB/s (gap).

constexpr int NBINS  = 2001;  // BIN_SIZE + 1
constexpr int DIM    = 128;
constexpr int CHUNKS = 4;     // bin-range chunks per sample -> 2048 blocks

typedef float v4f __attribute__((ext_vector_type(4)));

__global__ __launch_bounds__(256) void chrom_embed_bcast(
    const int* __restrict__ chr,
    const float* __restrict__ ce,
    float* __restrict__ out,
    int bins_per_chunk)
{
    const int b   = blockIdx.y;        // sample 0..511
    const int row = chr[b] - 1;        // 0..23

    const int lane_f4 = threadIdx.x & 31;   // float4 slot within the 128-f row
    const int sub     = threadIdx.x >> 5;   // 0..7: bin-row within 8-row group

    const v4f val = ((const v4f*)(ce + (size_t)row * DIM))[lane_f4];

    int bin_start = blockIdx.x * bins_per_chunk;
    int bin_end   = bin_start + bins_per_chunk;
    if (bin_end > NBINS) bin_end = NBINS;

    v4f* out_b = (v4f*)(out + (size_t)b * NBINS * DIM);

    int bin = bin_start + sub;
    for (; bin + 24 < bin_end; bin += 32) {
        __builtin_nontemporal_store(val, &out_b[(size_t)(bin     ) * (DIM / 4) + lane_f4]);
        __builtin_nontemporal_store(val, &out_b[(size_t)(bin +  8) * (DIM / 4) + lane_f4]);
        __builtin_nontemporal_store(val, &out_b[(size_t)(bin + 16) * (DIM / 4) + lane_f4]);
        __builtin_nontemporal_store(val, &out_b[(size_t)(bin + 24) * (DIM / 4) + lane_f4]);
    }
    for (; bin < bin_end; bin += 8) {
        __builtin_nontemporal_store(val, &out_b[(size_t)bin * (DIM / 4) + lane_f4]);
    }
}

extern "C" void kernel_launch(void* const* d_in, const int* in_sizes, int n_in,
                              void* d_out, int out_size, void* d_ws, size_t ws_size,
                              hipStream_t stream)
{
    // setup_inputs order: tensor (unused), chr, ce
    const int*   chr = (const int*)d_in[1];
    const float* ce  = (const float*)d_in[2];
    float*       out = (float*)d_out;

    const int bs = in_sizes[1];                                // 512
    const int bins_per_chunk = (NBINS + CHUNKS - 1) / CHUNKS;  // 501

    dim3 grid(CHUNKS, bs);
    // Real output (graded):
    chrom_embed_bcast<<<grid, 256, 0, stream>>>(chr, ce, out, bins_per_chunk);

    // Diagnostic: identical second sweep into workspace to measure marginal
    // store BW. ws_size is constant across calls, so work is call-invariant.
    if (ws_size >= (size_t)out_size * sizeof(float)) {
        chrom_embed_bcast<<<grid, 256, 0, stream>>>(chr, ce, (float*)d_ws, bins_per_chunk);
    }
}

// Round 5
// 515.336 us; speedup vs baseline: 1.1891x; 1.1891x over previous
//
#include <hip/hip_runtime.h>

// out[b, bin, d] = ce[chr[b]-1, d]; tensor (512,2001) unused, chr (512,) i32,
// ce (24,128) f32, out (512,2001,128) f32 = 524.5 MB. Pure write-BW-bound.
// v5 = v3 (diagnostic second launch reverted). Measured marginal kernel cost
// ~101 us for 524.5 MB => ~5.2-6 TB/s streaming stores, ~85-95% of the
// 6.34 TB/s achievable write BW (harness fill kernel reference). Remaining
// dur_us is fixed harness cost (331 us re-poison fill + replay overhead).

constexpr int NBINS  = 2001;  // BIN_SIZE + 1
constexpr int DIM    = 128;
constexpr int CHUNKS = 4;     // bin-range chunks per sample -> 2048 blocks

typedef float v4f __attribute__((ext_vector_type(4)));

__global__ __launch_bounds__(256) void chrom_embed_bcast(
    const int* __restrict__ chr,
    const float* __restrict__ ce,
    float* __restrict__ out,
    int bins_per_chunk)
{
    const int b   = blockIdx.y;        // sample 0..511
    const int row = chr[b] - 1;        // 0..23

    const int lane_f4 = threadIdx.x & 31;   // float4 slot within the 128-f row
    const int sub     = threadIdx.x >> 5;   // 0..7: bin-row within 8-row group

    const v4f val = ((const v4f*)(ce + (size_t)row * DIM))[lane_f4];

    int bin_start = blockIdx.x * bins_per_chunk;
    int bin_end   = bin_start + bins_per_chunk;
    if (bin_end > NBINS) bin_end = NBINS;

    v4f* out_b = (v4f*)(out + (size_t)b * NBINS * DIM);

    // 4 independent 16B nt-stores per thread per iteration; each wave covers
    // 1KB contiguous per store instruction, block covers 4KB per sub-step.
    int bin = bin_start + sub;
    for (; bin + 24 < bin_end; bin += 32) {
        __builtin_nontemporal_store(val, &out_b[(size_t)(bin     ) * (DIM / 4) + lane_f4]);
        __builtin_nontemporal_store(val, &out_b[(size_t)(bin +  8) * (DIM / 4) + lane_f4]);
        __builtin_nontemporal_store(val, &out_b[(size_t)(bin + 16) * (DIM / 4) + lane_f4]);
        __builtin_nontemporal_store(val, &out_b[(size_t)(bin + 24) * (DIM / 4) + lane_f4]);
    }
    for (; bin < bin_end; bin += 8) {
        __builtin_nontemporal_store(val, &out_b[(size_t)bin * (DIM / 4) + lane_f4]);
    }
}

extern "C" void kernel_launch(void* const* d_in, const int* in_sizes, int n_in,
                              void* d_out, int out_size, void* d_ws, size_t ws_size,
                              hipStream_t stream)
{
    // setup_inputs order: tensor (unused), chr, ce
    const int*   chr = (const int*)d_in[1];
    const float* ce  = (const float*)d_in[2];
    float*       out = (float*)d_out;

    const int bs = in_sizes[1];                                // 512
    const int bins_per_chunk = (NBINS + CHUNKS - 1) / CHUNKS;  // 501

    dim3 grid(CHUNKS, bs);
    chrom_embed_bcast<<<grid, 256, 0, stream>>>(chr, ce, out, bins_per_chunk);
}